// Round 5
// baseline (354.345 us; speedup 1.0000x reference)
//
#include <hip/hip_runtime.h>

// BMM_S8T_S8N_F16T: out[b,m,n] = fp16-range(alpha * sum_k A[b,m,k]*B[b,n,k])
// A: (B,M,K) int32 (int8-range), B: (B,N,K) int32, out: float. B=64, M=N=1024, K=128.
//
// Roofline: 268 MB write + 67 MB read => ~53 us @6.3 TB/s. Write-dominated.
// R5/R6/R8 (~165 us kernel) and R9 (~150 us, full-line nt stores, -13) are
//   nearly schedule-invariant. Compute/LDS cycle-counts to ~8 us/CU; the
//   ~100 us gap is unexplained, and the kernel has NEVER appeared in the
//   rocprof top-5 (fills ~170 us dominate) -> all steering was inference.
// R10 = MEASUREMENT PROBE: R9 + a duplicated store pass per chunk (same
//   values, same addresses; pointer laundered via asm so it can't be
//   deduped). Correct (idempotent). Purpose:
//   (a) dispatch grows ~+1x 268MB write pass -> kernel becomes top-5 visible
//       with real FETCH_SIZE/WRITE_SIZE/MfmaUtil/VALUBusy/Occupancy;
//   (b) dur(R10)-dur(R9) = marginal cost of 268MB pure nt-write stream:
//       ~45us -> store path at fill rate, stores exonerated;
//       ~100-130us -> store path ~2TB/s confirmed as the throttle;
//       WRITE_SIZE >> 536MB -> write amplification (sector/RFO) indicted.

#define Mdim 1024
#define Ndim 1024
#define Kdim 128
#define NROWS 16     // m-rows per strip
#define NSTRIPS 16   // strips per block -> 256 m-rows
#define BSTRIDE 128  // packed bytes per B row (no pad; XOR swizzle instead)

using int32x4 = __attribute__((ext_vector_type(4))) int;
using floatx4 = __attribute__((ext_vector_type(4))) float;

__device__ __forceinline__ unsigned pack8(int32x4 v) {
    return (unsigned)(v.x & 255) | ((unsigned)(v.y & 255) << 8)
         | ((unsigned)(v.z & 255) << 16) | ((unsigned)(v.w & 255) << 24);
}

// B-tile swizzle: XOR row&7 into the 16-B-unit bits (bijective per row).
__device__ __forceinline__ int swz(int byte_off) {
    return byte_off ^ (((byte_off >> 7) & 7) << 4);
}

// LDS-only barrier: no vmcnt drain -> in-flight global stores keep streaming.
__device__ __forceinline__ void lds_barrier() {
    asm volatile("s_waitcnt lgkmcnt(0)\n\ts_barrier" ::: "memory");
}

__global__ __launch_bounds__(512, 2)
void bmm_s8_kernel(const int* __restrict__ A, const int* __restrict__ Bm,
                   const float* __restrict__ alpha_p, float* __restrict__ out)
{
    __shared__ unsigned char Bs[1024 * BSTRIDE];  // 128 KiB: full B, packed int8
    __shared__ int32x4 Cs4[1024];                 // 16 KiB: 4-row f32 chunk (transpose buf)
    unsigned char* const Cs = (unsigned char*)Cs4;

    const int t    = threadIdx.x;
    const int z    = blockIdx.x;   // batch; linear%8 == z%8 -> per-XCD batch affinity
    const int q    = blockIdx.y;   // m-quarter: rows [q*256, q*256+256)
    const int lane = t & 63;
    const int wave = t >> 6;       // 0..7
    const int wn   = wave * 128;   // this wave's n band

    const int* __restrict__ Ab = A  + (size_t)z * Mdim * Kdim + (size_t)(q * 256) * Kdim;
    const int* __restrict__ Bb = Bm + (size_t)z * Ndim * Kdim;
    float* __restrict__ Ob     = out + (size_t)z * Mdim * Ndim + (size_t)(q * 256) * Ndim;

    const int r = lane & 15;   // fragment row within 16 (m-row), also D col owner
    const int g = lane >> 4;   // fragment k-chunk selector, also D 4-col group

    // ---- issue A prefetch for strip 0 (oldest loads; land during staging) ----
    int32x4 araw[8];
#pragma unroll
    for (int k = 0; k < 8; ++k) {
        const int ks = k >> 2, i = k & 3;
        araw[k] = *(const int32x4*)(Ab + (size_t)r * Kdim + ks * 64 + g * 16 + i * 4);
    }

    // ---- stage FULL B (1024 rows x 32 16-B chunks = 32768 chunks) ----
#pragma unroll 1
    for (int rr = 0; rr < 4; ++rr) {
        int32x4 breg[16];
#pragma unroll
        for (int j = 0; j < 16; ++j) {
            const int f    = t + 512 * (rr * 16 + j);
            const int row  = f >> 5;
            const int colb = (f & 31) * 4;
            breg[j] = *(const int32x4*)(Bb + (size_t)row * Kdim + colb);
        }
#pragma unroll
        for (int j = 0; j < 16; ++j) {
            const int f    = t + 512 * (rr * 16 + j);
            const int row  = f >> 5;
            const int colb = (f & 31) * 4;
            *(unsigned*)(&Bs[swz(row * BSTRIDE + colb)]) = pack8(breg[j]);
        }
    }
    __syncthreads();

    const float alpha = alpha_p[0];

#pragma unroll 1
    for (int s = 0; s < NSTRIPS; ++s) {
        // consume prefetched A into fragments
        int32x4 af[2];
#pragma unroll
        for (int ks = 0; ks < 2; ++ks)
            af[ks] = (int32x4){ (int)pack8(araw[ks * 4 + 0]), (int)pack8(araw[ks * 4 + 1]),
                                (int)pack8(araw[ks * 4 + 2]), (int)pack8(araw[ks * 4 + 3]) };

        // issue next strip's A loads (in flight across compute + stores)
        if (s + 1 < NSTRIPS) {
            const int* __restrict__ An = Ab + (size_t)((s + 1) * NROWS) * Kdim;
#pragma unroll
            for (int k = 0; k < 8; ++k) {
                const int ks = k >> 2, i = k & 3;
                araw[k] = *(const int32x4*)(An + (size_t)r * Kdim + ks * 64 + g * 16 + i * 4);
            }
        }

        // ---- MFMA: wave computes 16(m) x 128(n) of this strip ----
        int32x4 acc[8];
#pragma unroll
        for (int nt = 0; nt < 8; ++nt)
            acc[nt] = (int32x4){0, 0, 0, 0};

#pragma unroll
        for (int ks = 0; ks < 2; ++ks) {
#pragma unroll
            for (int nt = 0; nt < 8; ++nt) {
                const int row = wn + nt * 16 + r;
                int32x4 bf = *(const int32x4*)(&Bs[swz(row * BSTRIDE + ks * 64 + g * 16)]);
                acc[nt] = __builtin_amdgcn_mfma_i32_16x16x64_i8(bf, af[ks], acc[nt], 0, 0, 0);
            }
        }

        // convert once: lane holds out[m=r][n = wn + nt*16 + g*4 + j]
        floatx4 facc[8];
#pragma unroll
        for (int nt = 0; nt < 8; ++nt) {
            facc[nt].x = alpha * (float)acc[nt][0];
            facc[nt].y = alpha * (float)acc[nt][1];
            facc[nt].z = alpha * (float)acc[nt][2];
            facc[nt].w = alpha * (float)acc[nt][3];
        }

        // ---- epilogue: 4 chunks of 4 rows; transpose via LDS, store as
        //      1-KB-contiguous-per-instruction nontemporal full-line writes ----
#pragma unroll
        for (int c = 0; c < 4; ++c) {
            if ((r >> 2) == c) {
                const int rowL = r & 3;
                const int xo   = (rowL & 3) << 4;
#pragma unroll
                for (int nt = 0; nt < 8; ++nt) {
                    const int off = rowL * 4096 + wn * 4 + nt * 64 + g * 16;
                    *(floatx4*)(&Cs[off ^ xo]) = facc[nt];
                }
            }
            lds_barrier();  // chunk data visible; stores below never drained here

            const size_t basef = (size_t)(s * NROWS + c * 4) * Ndim;  // float index

            // pass 1: the real store
#pragma unroll
            for (int p = 0; p < 2; ++p) {
                const int off  = (t + p * 512) * 16;       // byte offset in 16-KB chunk
                const int rowL = off >> 12;
                floatx4 v = *(const floatx4*)(&Cs[off ^ ((rowL & 3) << 4)]);
                __builtin_nontemporal_store(v, (floatx4*)(Ob + basef + (off >> 2)));
            }

            // pass 2 (PROBE): identical values to identical addresses, pointer
            // laundered so the compiler cannot prove redundancy. Idempotent.
#pragma unroll
            for (int p = 0; p < 2; ++p) {
                const int off  = (t + p * 512) * 16;
                const int rowL = off >> 12;
                floatx4 v = *(const floatx4*)(&Cs[off ^ ((rowL & 3) << 4)]);
                unsigned long long dsti = (unsigned long long)(Ob + basef + (off >> 2));
                asm volatile("" : "+v"(dsti));
                __builtin_nontemporal_store(v, (floatx4*)dsti);
            }

            lds_barrier();  // reads done before next chunk overwrites Cs
        }
    }
}

extern "C" void kernel_launch(void* const* d_in, const int* in_sizes, int n_in,
                              void* d_out, int out_size, void* d_ws, size_t ws_size,
                              hipStream_t stream) {
    const int*   a     = (const int*)d_in[0];
    const int*   b     = (const int*)d_in[1];
    const float* alpha = (const float*)d_in[2];
    float*       out   = (float*)d_out;

    const int batch = in_sizes[0] / (Mdim * Kdim);  // 64
    dim3 grid(batch, Mdim / (NROWS * NSTRIPS));     // (64, 4): 256 blocks = 1/CU
    bmm_s8_kernel<<<grid, 512, 0, stream>>>(a, b, alpha, out);
}

// Round 6
// 346.618 us; speedup vs baseline: 1.0223x; 1.0223x over previous
//
#include <hip/hip_runtime.h>

// BMM_S8T_S8N_F16T: out[b,m,n] = fp16-range(alpha * sum_k A[b,m,k]*B[b,n,k])
// A: (B,M,K) int32 (int8-range), B: (B,N,K) int32, out: float. B=64, M=N=1024, K=128.
//
// Roofline: 268 MB write + 67 MB read => ~53 us @6.3 TB/s. Write-dominated.
// R5-R9: schedule-invariant ~150-165 us kernel. R10 PROBE: duplicated the
//   entire 268-MB nt-store pass -> only +23.7 us, and kernel still absent
//   from rocprof top-5 (<164 us). STORES EXONERATED (~25-45 us real cost).
//   Revised model: no single sink; residual is phase SERIALIZATION at
//   1 block/CU (144 KB LDS): stage (20-30us, no overlap) -> [compute ->
//   128 barrier-paced chunk stores] all serial, 2 waves/SIMD.
// R11: 2 blocks/CU. Block = (z batch, q m-quarter, h n-half): 256m x 512n,
//   stages 512 B-rows (64 KB) + 8 KB C-chunk = 72 KB LDS -> 2 resident
//   blocks/CU, 4 waves/SIMD. Resident blocks run phase-shifted: one's
//   staging/barriers hide under the other's MFMA/stores. All 8 blocks of
//   batch z share XCD z%8 L2 for B. launch_bounds(512,4) caps VGPR at 128
//   (staging rounds shrunk to 8 loads to fit). Store path keeps R9's
//   full-line nt geometry (2-KB contiguous per row, LDS-transposed).

#define Mdim 1024
#define Ndim 1024
#define Kdim 128
#define NROWS 16     // m-rows per strip
#define NSTRIPS 16   // strips per block -> 256 m-rows
#define HROWS 512    // B rows (n) staged per block = n-half
#define BSTRIDE 128  // packed bytes per B row

using int32x4 = __attribute__((ext_vector_type(4))) int;
using floatx4 = __attribute__((ext_vector_type(4))) float;

__device__ __forceinline__ unsigned pack8(int32x4 v) {
    return (unsigned)(v.x & 255) | ((unsigned)(v.y & 255) << 8)
         | ((unsigned)(v.z & 255) << 16) | ((unsigned)(v.w & 255) << 24);
}

// B-tile swizzle: XOR row&7 into the 16-B-unit bits (bijective per row).
__device__ __forceinline__ int swz(int byte_off) {
    return byte_off ^ (((byte_off >> 7) & 7) << 4);
}

// LDS-only barrier: no vmcnt drain -> in-flight global stores keep streaming.
__device__ __forceinline__ void lds_barrier() {
    asm volatile("s_waitcnt lgkmcnt(0)\n\ts_barrier" ::: "memory");
}

__global__ __launch_bounds__(512, 4)
void bmm_s8_kernel(const int* __restrict__ A, const int* __restrict__ Bm,
                   const float* __restrict__ alpha_p, float* __restrict__ out)
{
    __shared__ unsigned char Bs[HROWS * BSTRIDE];  // 64 KiB: half-B, packed int8
    __shared__ int32x4 Cs4[512];                   // 8 KiB: 4-row x 512-n f32 chunk
    unsigned char* const Cs = (unsigned char*)Cs4;

    const int t    = threadIdx.x;
    const int z    = blockIdx.x;   // batch; linear%8 == z%8 -> per-XCD batch affinity
    const int q    = blockIdx.y;   // m-quarter: rows [q*256, q*256+256)
    const int h    = blockIdx.z;   // n-half: cols [h*512, h*512+512)
    const int lane = t & 63;
    const int wave = t >> 6;       // 0..7
    const int wn   = wave * 64;    // wave's n band within the half

    const int* __restrict__ Ab = A  + (size_t)z * Mdim * Kdim + (size_t)(q * 256) * Kdim;
    const int* __restrict__ Bb = Bm + (size_t)z * Ndim * Kdim + (size_t)(h * HROWS) * Kdim;
    float* __restrict__ Ob     = out + (size_t)z * Mdim * Ndim + (size_t)(q * 256) * Ndim
                                     + (size_t)(h * HROWS);

    const int r = lane & 15;   // fragment m-row within 16
    const int g = lane >> 4;   // fragment k-chunk / 4-col group

    // ---- issue A prefetch for strip 0 (oldest loads; land during staging) ----
    int32x4 araw[8];
#pragma unroll
    for (int k = 0; k < 8; ++k) {
        const int ks = k >> 2, i = k & 3;
        araw[k] = *(const int32x4*)(Ab + (size_t)r * Kdim + ks * 64 + g * 16 + i * 4);
    }

    // ---- stage half-B (512 rows x 32 16-B chunks = 16384 chunks) ----
    // 512 threads x 32 chunks, 4 rounds of {8 loads, 8 packed stores} (VGPR cap).
#pragma unroll 1
    for (int rr = 0; rr < 4; ++rr) {
        int32x4 breg[8];
#pragma unroll
        for (int j = 0; j < 8; ++j) {
            const int f    = t + 512 * (rr * 8 + j);
            const int row  = f >> 5;             // 0..511 across rounds
            const int colb = (f & 31) * 4;
            breg[j] = *(const int32x4*)(Bb + (size_t)row * Kdim + colb);
        }
#pragma unroll
        for (int j = 0; j < 8; ++j) {
            const int f    = t + 512 * (rr * 8 + j);
            const int row  = f >> 5;
            const int colb = (f & 31) * 4;
            *(unsigned*)(&Bs[swz(row * BSTRIDE + colb)]) = pack8(breg[j]);
        }
    }
    __syncthreads();

    const float alpha = alpha_p[0];

#pragma unroll 1
    for (int s = 0; s < NSTRIPS; ++s) {
        // consume prefetched A into fragments
        int32x4 af[2];
#pragma unroll
        for (int ks = 0; ks < 2; ++ks)
            af[ks] = (int32x4){ (int)pack8(araw[ks * 4 + 0]), (int)pack8(araw[ks * 4 + 1]),
                                (int)pack8(araw[ks * 4 + 2]), (int)pack8(araw[ks * 4 + 3]) };

        // issue next strip's A loads (in flight across compute + stores)
        if (s + 1 < NSTRIPS) {
            const int* __restrict__ An = Ab + (size_t)((s + 1) * NROWS) * Kdim;
#pragma unroll
            for (int k = 0; k < 8; ++k) {
                const int ks = k >> 2, i = k & 3;
                araw[k] = *(const int32x4*)(An + (size_t)r * Kdim + ks * 64 + g * 16 + i * 4);
            }
        }

        // ---- MFMA: wave computes 16(m) x 64(n) of this strip ----
        int32x4 acc[4];
#pragma unroll
        for (int nt = 0; nt < 4; ++nt)
            acc[nt] = (int32x4){0, 0, 0, 0};

#pragma unroll
        for (int ks = 0; ks < 2; ++ks) {
#pragma unroll
            for (int nt = 0; nt < 4; ++nt) {
                const int row = wn + nt * 16 + r;
                int32x4 bf = *(const int32x4*)(&Bs[swz(row * BSTRIDE + ks * 64 + g * 16)]);
                // swapped operands: D cols = m (lane&15), regs = 4 consecutive n
                acc[nt] = __builtin_amdgcn_mfma_i32_16x16x64_i8(bf, af[ks], acc[nt], 0, 0, 0);
            }
        }

        floatx4 facc[4];
#pragma unroll
        for (int nt = 0; nt < 4; ++nt) {
            facc[nt].x = alpha * (float)acc[nt][0];
            facc[nt].y = alpha * (float)acc[nt][1];
            facc[nt].z = alpha * (float)acc[nt][2];
            facc[nt].w = alpha * (float)acc[nt][3];
        }

        // ---- epilogue: 4 chunks of 4 rows x 512 n; transpose via LDS, store
        //      as full-line nontemporal writes (2-KB contiguous per row) ----
#pragma unroll
        for (int c = 0; c < 4; ++c) {
            if ((r >> 2) == c) {
                const int rowL = r & 3;
                const int xo   = rowL << 4;
#pragma unroll
                for (int nt = 0; nt < 4; ++nt) {
                    // lane holds out[m=r][n = wn + nt*16 + g*4 + 0..3]
                    const int off = rowL * 2048 + wn * 4 + nt * 64 + g * 16;
                    *(floatx4*)(&Cs[off ^ xo]) = facc[nt];
                }
            }
            lds_barrier();  // chunk visible; global stores never drained here

            {
                const int off  = t * 16;            // 512 thr x 16 B = 8 KB chunk
                const int rowL = off >> 11;         // 2048 B per chunk-row
                floatx4 v = *(const floatx4*)(&Cs[off ^ ((rowL & 3) << 4)]);
                const size_t basef = (size_t)(s * NROWS + c * 4) * Ndim;
                __builtin_nontemporal_store(
                    v, (floatx4*)(Ob + basef + (size_t)rowL * Ndim + ((off & 2047) >> 2)));
            }

            lds_barrier();  // reads done before next chunk overwrites Cs
        }
    }
}

extern "C" void kernel_launch(void* const* d_in, const int* in_sizes, int n_in,
                              void* d_out, int out_size, void* d_ws, size_t ws_size,
                              hipStream_t stream) {
    const int*   a     = (const int*)d_in[0];
    const int*   b     = (const int*)d_in[1];
    const float* alpha = (const float*)d_in[2];
    float*       out   = (float*)d_out;

    const int batch = in_sizes[0] / (Mdim * Kdim);  // 64
    dim3 grid(batch, Mdim / (NROWS * NSTRIPS), Ndim / HROWS);  // (64,4,2): 512 blocks, 2/CU
    bmm_s8_kernel<<<grid, 512, 0, stream>>>(a, b, alpha, out);
}